// Round 2
// baseline (838.758 us; speedup 1.0000x reference)
//
#include <hip/hip_runtime.h>

// RecursiveLSTM: B=1024 independent sequences, T=96, H=50, num_pred=12.
// One block per batch element; 1152 serial LSTM steps inside the kernel.
// Thread j<200 owns gate j. W_hh row held in 13 *named* float4 VGPR locals
// (SROA-proof; round-1's w[52] array was demoted to scratch -> VGPR_Count 36).
// Each wave keeps a private h copy in LDS + redundant c update => 1 barrier/step.

#define HSZ   50
#define G4    200      // 4*H gates
#define TLEN  96
#define MAXP  16       // >= num_pred

__device__ __forceinline__ float tanh_(float x) {
    // 1 - 2/(exp(2x)+1): no inf/inf NaN at large |x|
    return 1.0f - 2.0f / (__expf(2.0f * x) + 1.0f);
}

__global__ __launch_bounds__(256, 4)
void rec_lstm_kernel(const float* __restrict__ x,
                     const float* __restrict__ W_ih,
                     const float* __restrict__ W_hh,
                     const float* __restrict__ b_ih,
                     const float* __restrict__ b_hh,
                     const float* __restrict__ W_fc,
                     const float* __restrict__ b_fc,
                     const int*   __restrict__ num_pred,
                     float*       __restrict__ out)
{
    const int b    = blockIdx.x;
    const int tid  = threadIdx.x;
    const int wave = tid >> 6;
    const int lane = tid & 63;

    __shared__ float x_lds[TLEN];
    __shared__ float preds[MAXP];
    __shared__ __align__(16) float hbuf[4][52];   // per-wave h copy (13 float4)
    __shared__ float gates[2][G4];                // double-buffered (1 barrier/step)

    // ---- one-time preload ----
    const int  gsafe = (tid < G4) ? tid : 0;
    const float* wr  = W_hh + gsafe * HSZ;
    float4 wA0, wA1, wA2, wA3, wA4, wA5, wA6, wA7, wA8, wA9, wA10, wA11, wA12;
#define LDW(i) wA##i = make_float4(wr[4*(i)], wr[4*(i)+1], wr[4*(i)+2], wr[4*(i)+3])
    LDW(0); LDW(1); LDW(2); LDW(3); LDW(4); LDW(5); LDW(6); LDW(7);
    LDW(8); LDW(9); LDW(10); LDW(11);
    wA12 = make_float4(wr[48], wr[49], 0.f, 0.f);
#undef LDW
    const float wih  = W_ih[gsafe];
    const float bsum = b_ih[gsafe] + b_hh[gsafe];
    const float wfc  = W_fc[(lane < HSZ) ? lane : 0];
    if (tid < TLEN) x_lds[tid] = x[b * TLEN + tid];
    const float bfc = b_fc[0];
    const int   NP  = num_pred[0];

    // gate nonlinearity fused: a = m*sigmoid(m*acc) + (1-m); m=2 -> tanh, m=1 -> sigmoid
    const float m_   = (tid >= 100 && tid < 150) ? 2.0f : 1.0f;
    const float add_ = 1.0f - m_;

    float c   = 0.f;   // per-wave-redundant cell state (lanes < 50)
    int   par = 0;

    __syncthreads();   // x_lds visible

    for (int p = 0; p < NP; ++p) {
        if (lane < 52) hbuf[wave][lane] = 0.f;    // wave-private: no barrier needed
        c = 0.f;

        for (int t = 0; t < TLEN; ++t) {
            const int idx = p + t;                       // sliding window
            const float xv = (idx < TLEN) ? x_lds[idx] : preds[idx - TLEN];

            if (tid < G4) {
                float acc = fmaf(wih, xv, bsum);
                const float4* hb4 = (const float4*)&hbuf[wave][0];  // broadcast reads
#define ACC(i) { float4 hv = hb4[i]; \
                 acc = fmaf(wA##i.x, hv.x, acc); acc = fmaf(wA##i.y, hv.y, acc); \
                 acc = fmaf(wA##i.z, hv.z, acc); acc = fmaf(wA##i.w, hv.w, acc); }
                ACC(0) ACC(1) ACC(2) ACC(3) ACC(4) ACC(5) ACC(6)
                ACC(7) ACC(8) ACC(9) ACC(10) ACC(11) ACC(12)
#undef ACC
                const float sig = 1.0f / (1.0f + __expf(-m_ * acc));
                gates[par][tid] = fmaf(m_, sig, add_);
            }
            __syncthreads();   // gates from all waves visible

            if (lane < HSZ) {  // ALL waves: redundant update into private h copy
                const float gi = gates[par][lane];
                const float gf = gates[par][lane + 50];
                const float gg = gates[par][lane + 100];
                const float go = gates[par][lane + 150];
                c = fmaf(gf, c, gi * gg);
                hbuf[wave][lane] = go * tanh_(c);
            }
            par ^= 1;          // next step writes the other gate buffer
        }

        // ---- FC head: every wave has a full h copy; wave 0 reduces ----
        if (wave == 0) {
            float v = (lane < HSZ) ? hbuf[0][lane] * wfc : 0.f;
            #pragma unroll
            for (int off = 32; off >= 1; off >>= 1)
                v += __shfl_down(v, off, 64);
            if (lane == 0) {
                const float pr = v + bfc;
                preds[p] = pr;
                out[b * NP + p] = pr;
            }
        }
        __syncthreads();   // preds visible before next pass reads it
    }
}

extern "C" void kernel_launch(void* const* d_in, const int* in_sizes, int n_in,
                              void* d_out, int out_size, void* d_ws, size_t ws_size,
                              hipStream_t stream)
{
    const float* x    = (const float*)d_in[0];
    const float* W_ih = (const float*)d_in[1];
    const float* W_hh = (const float*)d_in[2];
    const float* b_ih = (const float*)d_in[3];
    const float* b_hh = (const float*)d_in[4];
    const float* W_fc = (const float*)d_in[5];
    const float* b_fc = (const float*)d_in[6];
    const int*   np   = (const int*)d_in[7];
    float* out = (float*)d_out;

    const int B = in_sizes[0] / TLEN;   // 1024
    rec_lstm_kernel<<<B, 256, 0, stream>>>(x, W_ih, W_hh, b_ih, b_hh,
                                           W_fc, b_fc, np, out);
}